// Round 9
// baseline (285.026 us; speedup 1.0000x reference)
//
#include <hip/hip_runtime.h>
#include <math.h>

#define N_NODES 100000
#define N_EDGES 1600000
#define FDIM 128
#define NHEAD 8
#define HDIM 16
#define SCAT_PHASES 4
#define CNT_STRIDE 16      // one counter per 64B line
#define NXCD 8
#define NODES_PER_XCD (N_NODES / NXCD)   // 12500
#define CHUNK_EDGES 4096

using bf16x8 = __attribute__((ext_vector_type(8))) short;
using half8  = __attribute__((ext_vector_type(8))) _Float16;
using f32x4  = __attribute__((ext_vector_type(4))) float;
using f32x2  = __attribute__((ext_vector_type(2))) float;

__device__ inline unsigned short f2bf(float f) {
    union { float f; unsigned int u; } x; x.f = f;
    unsigned int u = x.u;
    return (unsigned short)((u + 0x7fffu + ((u >> 16) & 1u)) >> 16);   // RNE
}
__device__ inline unsigned short f2h(float f) {
    _Float16 h = (_Float16)f;
    return __builtin_bit_cast(unsigned short, h);
}
__device__ inline unsigned int packh2(float a, float b) {
    return (unsigned int)f2h(a) | ((unsigned int)f2h(b) << 16);
}
__device__ inline float h_lo(unsigned int u) {
    return (float)__builtin_bit_cast(_Float16, (unsigned short)(u & 0xffffu));
}
__device__ inline float h_hi(unsigned int u) {
    return (float)__builtin_bit_cast(_Float16, (unsigned short)(u >> 16));
}
__device__ inline float exp2_fast(float x) {
#if __has_builtin(__builtin_amdgcn_exp2f)
    return __builtin_amdgcn_exp2f(x);
#else
    return __expf(x * 0.6931471805599453f);
#endif
}

// ---- fp8 e4m3 encode/decode (HW cvt on gfx950; SW fallback) ---------------
#if __has_builtin(__builtin_amdgcn_cvt_pk_fp8_f32)
__device__ inline unsigned char fp8_enc(float x) {
    return (unsigned char)(__builtin_amdgcn_cvt_pk_fp8_f32(x, x, 0, false) & 0xff);
}
#else
__device__ inline unsigned char fp8_enc(float x) {
    unsigned int u = __builtin_bit_cast(unsigned int, x);
    unsigned int s = (u >> 24) & 0x80;
    float ax = fabsf(x);
    if (!(ax >= 0.001953125f)) {
        int m = (int)(ax * 512.f + 0.5f);
        return (unsigned char)(s | (unsigned)(m > 7 ? 7 : m));
    }
    if (ax > 448.f) return (unsigned char)(s | 0x7e);
    int e; float fr = frexpf(ax, &e);
    int q = (int)(fr * 16.f + 0.5f);
    if (q == 16) { q = 8; e += 1; }
    int exp = e - 1 + 7;
    if (exp <= 0) { int m = (int)(ax * 512.f + 0.5f); return (unsigned char)(s | (unsigned)(m > 7 ? 7 : m)); }
    if (exp > 15) return (unsigned char)(s | 0x7e);
    return (unsigned char)(s | (exp << 3) | (q & 7));
}
#endif

#if __has_builtin(__builtin_amdgcn_cvt_pk_f32_fp8)
#define FP8_HW_DECODE 1
#else
__device__ inline float fp8_dec_sw(unsigned char b) {
    int s = b >> 7, e = (b >> 3) & 15, m = b & 7;
    float v = (e == 0) ? ldexpf((float)m, -9) : ldexpf((float)(8 + m), e - 10);
    return s ? -v : v;
}
#endif

// dot of 16 fp8 (one head's k row, as uint4) with 16 f32 q values (as 8 pairs)
__device__ inline float dot_fp8_16(uint4 kr, const f32x2* __restrict__ qq2) {
#ifdef FP8_HW_DECODE
    f32x2 a = {0.f, 0.f};
    f32x2 p;
    p = __builtin_amdgcn_cvt_pk_f32_fp8(kr.x, false); a += p * qq2[0];
    p = __builtin_amdgcn_cvt_pk_f32_fp8(kr.x, true);  a += p * qq2[1];
    p = __builtin_amdgcn_cvt_pk_f32_fp8(kr.y, false); a += p * qq2[2];
    p = __builtin_amdgcn_cvt_pk_f32_fp8(kr.y, true);  a += p * qq2[3];
    p = __builtin_amdgcn_cvt_pk_f32_fp8(kr.z, false); a += p * qq2[4];
    p = __builtin_amdgcn_cvt_pk_f32_fp8(kr.z, true);  a += p * qq2[5];
    p = __builtin_amdgcn_cvt_pk_f32_fp8(kr.w, false); a += p * qq2[6];
    p = __builtin_amdgcn_cvt_pk_f32_fp8(kr.w, true);  a += p * qq2[7];
    return a[0] + a[1];
#else
    const float* qq = (const float*)qq2;
    float s = 0.f;
    unsigned int wds[4] = {kr.x, kr.y, kr.z, kr.w};
#pragma unroll
    for (int i = 0; i < 4; ++i)
#pragma unroll
        for (int j = 0; j < 4; ++j)
            s = fmaf(fp8_dec_sw((wds[i] >> (8 * j)) & 0xff), qq[i * 4 + j], s);
    return s;
#endif
}

// ---------------------------------------------------------------------------
// Weights -> frag-linear layout (round 5) + zero padded counters and tickets.
// ---------------------------------------------------------------------------
__global__ __launch_bounds__(256) void convert_w_kernel(
    const float* __restrict__ W0, const float* __restrict__ W1,
    const float* __restrict__ W2, const float* __restrict__ W3,
    unsigned short* __restrict__ out, int* __restrict__ cnt, int* __restrict__ tick)
{
    int i = blockIdx.x * 256 + threadIdx.x;   // 0..16383
    int j  = i & 7;
    int l  = (i >> 3) & 63;
    int fk = i >> 9;                           // 0..31
    int ks = fk & 3, nf = fk >> 2;
    int s = (nf * 16 + (l & 15)) * FDIM + ks * 32 + (l >> 4) * 8 + j;
    out[i]             = f2bf(W0[s]);
    out[16384 + i]     = f2bf(W1[s]);
    out[2 * 16384 + i] = f2bf(W2[s]);
    out[3 * 16384 + i] = f2h(W3[s]);
    for (int c = i; c < N_NODES; c += 64 * 256)
        cnt[(size_t)c * CNT_STRIDE] = 0;
    if (i < NXCD * CNT_STRIDE) tick[i] = 0;
}

// ---------------------------------------------------------------------------
// XCD-local edge count + rank. Each block reads its XCC_ID and handles ONLY
// edges whose dst lies in its XCD's node range, chunk-stealing over the edge
// list via a per-XCD ticket. All RMWs on a counter then originate from one
// XCD, so workgroup-scope atomics (which stay in the local L2, no fabric
// round-trip) are atomic-in-practice. rank8[i] = rank of edge i in its dst.
// ---------------------------------------------------------------------------
__global__ __launch_bounds__(256) void count_rank_xcd_kernel(
    const int* __restrict__ edst, int* __restrict__ cnt,
    unsigned char* __restrict__ rank8, int* __restrict__ tick, int n)
{
    __shared__ int c_s;
    unsigned xcd;
    asm("s_getreg_b32 %0, hwreg(HW_REG_XCC_ID, 0, 4)" : "=s"(xcd));
    xcd &= (NXCD - 1);
    const int lo = (int)xcd * NODES_PER_XCD;
    const int hi = lo + NODES_PER_XCD;

    for (;;) {
        if (threadIdx.x == 0)
            c_s = __hip_atomic_fetch_add(&tick[xcd * CNT_STRIDE], 1,
                                         __ATOMIC_RELAXED, __HIP_MEMORY_SCOPE_WORKGROUP);
        __syncthreads();
        const int base = c_s * CHUNK_EDGES;
        __syncthreads();               // c_s safe to overwrite next iteration
        if (base >= n) break;

#pragma unroll
        for (int g = 0; g < 4; ++g) {
            int i0 = base + threadIdx.x * 4 + g * 1024;
            if (i0 + 3 < n) {
                int4 d4 = *(const int4*)&edst[i0];
#pragma unroll
                for (int u = 0; u < 4; ++u) {
                    int d = (&d4.x)[u];
                    if (d >= lo && d < hi) {
                        int r = __hip_atomic_fetch_add(&cnt[(size_t)d * CNT_STRIDE], 1,
                                                       __ATOMIC_RELAXED, __HIP_MEMORY_SCOPE_WORKGROUP);
                        rank8[i0 + u] = (unsigned char)r;
                    }
                }
            } else {
                for (int u = 0; u < 4; ++u) {
                    int idx = i0 + u;
                    if (idx < n) {
                        int d = edst[idx];
                        if (d >= lo && d < hi) {
                            int r = __hip_atomic_fetch_add(&cnt[(size_t)d * CNT_STRIDE], 1,
                                                           __ATOMIC_RELAXED, __HIP_MEMORY_SCOPE_WORKGROUP);
                            rank8[idx] = (unsigned char)r;
                        }
                    }
                }
            }
        }
    }
}

// ---------------------------------------------------------------------------
// MFMA GEMM v2 (round 5 structure): latency-tolerant 128-row blocks.
// ---------------------------------------------------------------------------
struct GemmArgs {
    const unsigned short* W[3];
    const float* b[3];
    void* out[3];
    float scale[3];
};

template<int NP, bool IN_F32, bool MFMA_F16, int OUTM>
__global__ __launch_bounds__(256, 2) void mfma_gemm_v2(
    const void* __restrict__ Ain, GemmArgs ga, int nrows)
{
    __shared__ unsigned short A_s[128][136];   // 34816 B; reused for O repack
    __shared__ unsigned short W_sh[8192];      // 16 KB: half of one projection's W

    const int t  = threadIdx.x;
    const int r0 = blockIdx.x * 128;

#pragma unroll
    for (int it = 0; it < 8; ++it) {
        int i = t + it * 256;
        int r = i >> 4, c8 = (i & 15) << 3;
        int gr = r0 + r;
        if (IN_F32) {
            float4 v0 = make_float4(0.f, 0.f, 0.f, 0.f), v1 = v0;
            if (gr < nrows) {
                const float* Af = (const float*)Ain;
                v0 = *(const float4*)&Af[(size_t)gr * FDIM + c8];
                v1 = *(const float4*)&Af[(size_t)gr * FDIM + c8 + 4];
            }
            uint4 pk;
            pk.x = (unsigned)f2bf(v0.x) | ((unsigned)f2bf(v0.y) << 16);
            pk.y = (unsigned)f2bf(v0.z) | ((unsigned)f2bf(v0.w) << 16);
            pk.z = (unsigned)f2bf(v1.x) | ((unsigned)f2bf(v1.y) << 16);
            pk.w = (unsigned)f2bf(v1.z) | ((unsigned)f2bf(v1.w) << 16);
            *(uint4*)&A_s[r][c8] = pk;
        } else {
            uint4 v = make_uint4(0u, 0u, 0u, 0u);
            if (gr < nrows) {
                const unsigned short* Ab = (const unsigned short*)Ain;
                v = *(const uint4*)&Ab[(size_t)gr * FDIM + c8];
            }
            *(uint4*)&A_s[r][c8] = v;
        }
    }
    __syncthreads();

    const int w  = t >> 6, l = t & 63;
    const int lr = l & 15, lk = l >> 4;

    bf16x8 a[2][4];
#pragma unroll
    for (int rg = 0; rg < 2; ++rg)
#pragma unroll
        for (int ks = 0; ks < 4; ++ks)
            a[rg][ks] = *(const bf16x8*)&A_s[w * 32 + rg * 16 + lr][ks * 32 + lk * 8];

#pragma unroll
    for (int p = 0; p < NP; ++p) {
        const unsigned short* Wsrc = ga.W[p];
        f32x4 acc[2][8];
#pragma unroll
        for (int rg = 0; rg < 2; ++rg)
#pragma unroll
            for (int nf = 0; nf < 8; ++nf) acc[rg][nf] = (f32x4){0.f, 0.f, 0.f, 0.f};

#pragma unroll
        for (int h = 0; h < 2; ++h) {
#pragma unroll
            for (int it = 0; it < 4; ++it) {
                int chunk = t + it * 256;
                *(uint4*)&W_sh[chunk * 8] = *(const uint4*)&Wsrc[h * 8192 + chunk * 8];
            }
            __syncthreads();
#pragma unroll
            for (int nfl = 0; nfl < 4; ++nfl) {
                int nf = h * 4 + nfl;
#pragma unroll
                for (int ks = 0; ks < 4; ++ks) {
                    bf16x8 bfr = *(const bf16x8*)&W_sh[((nfl * 4 + ks) * 64 + l) * 8];
                    if (MFMA_F16) {
                        acc[0][nf] = __builtin_amdgcn_mfma_f32_16x16x32_f16(
                            __builtin_bit_cast(half8, a[0][ks]), __builtin_bit_cast(half8, bfr),
                            acc[0][nf], 0, 0, 0);
                        acc[1][nf] = __builtin_amdgcn_mfma_f32_16x16x32_f16(
                            __builtin_bit_cast(half8, a[1][ks]), __builtin_bit_cast(half8, bfr),
                            acc[1][nf], 0, 0, 0);
                    } else {
                        acc[0][nf] = __builtin_amdgcn_mfma_f32_16x16x32_bf16(a[0][ks], bfr, acc[0][nf], 0, 0, 0);
                        acc[1][nf] = __builtin_amdgcn_mfma_f32_16x16x32_bf16(a[1][ks], bfr, acc[1][nf], 0, 0, 0);
                    }
                }
            }
            __syncthreads();
        }

        const float* bias = ga.b[p];
        const float  scl  = ga.scale[p];
        const int    mode = (OUTM >> (2 * p)) & 3;

        if (mode == 0) {
            unsigned short* Oh = &A_s[0][0];
#pragma unroll
            for (int rg = 0; rg < 2; ++rg)
#pragma unroll
                for (int nf = 0; nf < 8; ++nf) {
                    int col = nf * 16 + lr;
                    float bv = bias[col];
#pragma unroll
                    for (int j = 0; j < 4; ++j)
                        Oh[(w * 32 + rg * 16 + lk * 4 + j) * 136 + col] = f2h((acc[rg][nf][j] + bv) * scl);
                }
            __syncthreads();
            unsigned short* outp = (unsigned short*)ga.out[p];
#pragma unroll
            for (int it = 0; it < 8; ++it) {
                int i = t + it * 256;
                int r = i >> 4, c8 = (i & 15) << 3;
                if (r0 + r < nrows)
                    *(uint4*)&outp[(size_t)(r0 + r) * FDIM + c8] = *(const uint4*)&Oh[r * 136 + c8];
            }
        } else if (mode == 1) {
            unsigned char* O8 = (unsigned char*)A_s;
#pragma unroll
            for (int rg = 0; rg < 2; ++rg)
#pragma unroll
                for (int nf = 0; nf < 8; ++nf) {
                    int col = nf * 16 + lr;
                    float bv = bias[col];
#pragma unroll
                    for (int j = 0; j < 4; ++j)
                        O8[(w * 32 + rg * 16 + lk * 4 + j) * 144 + col] = fp8_enc((acc[rg][nf][j] + bv) * scl);
                }
            __syncthreads();
            unsigned char* outp = (unsigned char*)ga.out[p];
#pragma unroll
            for (int it = 0; it < 4; ++it) {
                int i = t + it * 256;
                int r = i >> 3, c16 = (i & 7) << 4;
                if (r0 + r < nrows)
                    *(uint4*)&outp[(size_t)(r0 + r) * FDIM + c16] = *(const uint4*)&O8[r * 144 + c16];
            }
        } else {
            float* outp = (float*)ga.out[p];
#pragma unroll
            for (int rg = 0; rg < 2; ++rg)
#pragma unroll
                for (int nf = 0; nf < 8; ++nf) {
                    int col = nf * 16 + lr;
                    float bv = bias[col];
                    int row = r0 + w * 32 + rg * 16 + lk * 4;
#pragma unroll
                    for (int j = 0; j < 4; ++j)
                        if (row + j < nrows)
                            outp[(size_t)(row + j) * FDIM + col] = (acc[rg][nf][j] + bv) * scl;
                }
        }
    }
}

// ---------------------------------------------------------------------------
// Scan: block-local exclusive scan + per-block totals; consumers add
// part[d>>8] on the fly. cnt is read strided (line-padded counters).
// ---------------------------------------------------------------------------
__global__ void scan_a_kernel(const int* __restrict__ cnt, int* __restrict__ row_off,
                              int* __restrict__ part, int n)
{
    __shared__ int s[256];
    int t = threadIdx.x;
    int gid = blockIdx.x * 256 + t;
    int x = (gid < n) ? cnt[(size_t)gid * CNT_STRIDE] : 0;
    s[t] = x;
    __syncthreads();
    for (int off = 1; off < 256; off <<= 1) {
        int val = (t >= off) ? s[t - off] : 0;
        __syncthreads();
        s[t] += val;
        __syncthreads();
    }
    if (gid < n) row_off[gid] = s[t] - x;
    if (t == 255) part[blockIdx.x] = s[255];
}

__global__ void scan_b_kernel(int* __restrict__ part, int nb)
{
    __shared__ int s[512];
    int t = threadIdx.x;
    int x = (t < nb) ? part[t] : 0;
    s[t] = x;
    __syncthreads();
    for (int off = 1; off < 512; off <<= 1) {
        int val = (t >= off) ? s[t - off] : 0;
        __syncthreads();
        s[t] += val;
        __syncthreads();
    }
    if (t < nb) part[t] = s[t] - x;
}

// ---------------------------------------------------------------------------
// Single-launch phased scatter (reads edst + rank8 instead of packed pk).
// ---------------------------------------------------------------------------
__global__ void scatter_all_kernel(const int* __restrict__ src, const int* __restrict__ dst,
                                   const unsigned char* __restrict__ rank8,
                                   const int* __restrict__ row_off,
                                   const int* __restrict__ part,
                                   int* __restrict__ csr_src, int n, int blocksPerPhase)
{
    int phase = blockIdx.x / blocksPerPhase;
    int i = (blockIdx.x % blocksPerPhase) * 256 + threadIdx.x;
    if (i >= n) return;
    int lo = (N_NODES / SCAT_PHASES) * phase;
    int hi = lo + N_NODES / SCAT_PHASES;
    int d = __builtin_nontemporal_load(&dst[i]);
    if (d >= lo && d < hi) {
        int pos = row_off[d] + part[d >> 8] + (int)__builtin_nontemporal_load(&rank8[i]);
        csr_src[pos] = __builtin_nontemporal_load(&src[i]);
    }
}

// ---------------------------------------------------------------------------
// Fused edge-softmax attention (unchanged; no-max exp2 softmax).
// ---------------------------------------------------------------------------
__global__ __launch_bounds__(256) void attn_kernel(
    const unsigned short* __restrict__ q, const unsigned char* __restrict__ kf8,
    const unsigned short* __restrict__ v,
    const int* __restrict__ row_off, const int* __restrict__ part,
    const int* __restrict__ csr_src,
    unsigned short* __restrict__ out, int nnodes, int nedges)
{
    __shared__ float q_s[4][NHEAD][18];   // head stride 18 words: conflict-free
    __shared__ float p_s[4][64][NHEAD];
    __shared__ int   src_s[4][64];

    const int w = threadIdx.x >> 6;
    const int l = threadIdx.x & 63;
    const int node = blockIdx.x * 4 + w;
    if (node >= nnodes) return;

    {   // stage q row (pre-scaled by 0.25*log2e) as f32 pairs
        unsigned int qv = *(const unsigned int*)&q[(size_t)node * FDIM + l * 2];
        *(f32x2*)&q_s[w][l >> 3][(l & 7) * 2] = (f32x2){h_lo(qv), h_hi(qv)};
    }

    const int e_l = l >> 3, h_sc = l & 7;                    // score role
    const int e2 = l >> 4, h_ag = (l >> 1) & 7, dq = l & 1;  // agg role
    const int vo = h_ag * HDIM + dq * 8;                     // ushort offset

    const int start = row_off[node] + part[node >> 8];
    const int end   = (node == nnodes - 1) ? nedges
                      : row_off[node + 1] + part[(node + 1) >> 8];

    float z_run = 0.f;
    f32x2 acc[4] = {{0.f,0.f},{0.f,0.f},{0.f,0.f},{0.f,0.f}};   // 8 dims

    const f32x2* qq2 = (const f32x2*)&q_s[w][h_sc][0];

    for (int c0 = start; c0 < end; c0 += 64) {
        const int cn = min(64, end - c0);

        for (int i = l; i < cn; i += 64)
            src_s[w][i] = csr_src[c0 + i];

        // --- scores: p = exp2(k.q'), 4-deep batched 16B k loads -----------
        for (int base = 0; base < cn; base += 32) {
            uint4 kr[4];
#pragma unroll
            for (int it = 0; it < 4; ++it) {
                int ei = base + it * 8 + e_l;
                if (ei < cn)
                    kr[it] = *(const uint4*)&kf8[(size_t)src_s[w][ei] * FDIM + h_sc * 16];
            }
#pragma unroll
            for (int it = 0; it < 4; ++it) {
                int ei = base + it * 8 + e_l;
                if (ei < cn) {
                    float p = exp2_fast(dot_fp8_16(kr[it], qq2));
                    p_s[w][ei][h_sc] = p;
                    z_run += p;
                }
            }
        }

        // --- aggregation: 4 edges per iteration, 16B v load per lane ------
        for (int base = 0; base < cn; base += 4) {
            int e  = base + e2;
            int ec = min(e, cn - 1);
            float p = (e < cn) ? p_s[w][e][h_ag] : 0.f;
            uint4 vv = *(const uint4*)&v[(size_t)src_s[w][ec] * FDIM + vo];
            f32x2 p2 = {p, p};
            acc[0] += p2 * (f32x2){h_lo(vv.x), h_hi(vv.x)};
            acc[1] += p2 * (f32x2){h_lo(vv.y), h_hi(vv.y)};
            acc[2] += p2 * (f32x2){h_lo(vv.z), h_hi(vv.z)};
            acc[3] += p2 * (f32x2){h_lo(vv.w), h_hi(vv.w)};
        }
    }

    // z: sum across e_l groups (lanes sharing h_sc) — once per node
#pragma unroll
    for (int mask = 8; mask < 64; mask <<= 1)
        z_run += __shfl_xor(z_run, mask, 64);

    // acc: sum across the 4 e2 groups (masks 16, 32)
#pragma unroll
    for (int mask = 16; mask < 64; mask <<= 1)
#pragma unroll
        for (int i = 0; i < 4; ++i) {
            acc[i][0] += __shfl_xor(acc[i][0], mask, 64);
            acc[i][1] += __shfl_xor(acc[i][1], mask, 64);
        }

    float z_ag = __shfl(z_run, h_ag, 64);   // lane h_ag holds z for head h_ag

    if (e2 == 0) {
        uint4 o = make_uint4(0u, 0u, 0u, 0u);
        if (end > start) {
            float rz = 1.0f / z_ag;
            o.x = packh2(acc[0][0] * rz, acc[0][1] * rz);
            o.y = packh2(acc[1][0] * rz, acc[1][1] * rz);
            o.z = packh2(acc[2][0] * rz, acc[2][1] * rz);
            o.w = packh2(acc[3][0] * rz, acc[3][1] * rz);
        }
        *(uint4*)&out[(size_t)node * FDIM + vo] = o;
    }
}

// ---------------------------------------------------------------------------
extern "C" void kernel_launch(void* const* d_in, const int* in_sizes, int n_in,
                              void* d_out, int out_size, void* d_ws, size_t ws_size,
                              hipStream_t stream)
{
    const float* feat = (const float*)d_in[0];
    const int*   esrc = (const int*)d_in[1];
    const int*   edst = (const int*)d_in[2];
    const float* Wq   = (const float*)d_in[3];
    const float* bq   = (const float*)d_in[4];
    const float* Wk   = (const float*)d_in[5];
    const float* bk   = (const float*)d_in[6];
    const float* Wv   = (const float*)d_in[7];
    const float* bv   = (const float*)d_in[8];
    const float* Wo   = (const float*)d_in[9];
    const float* bo   = (const float*)d_in[10];
    float* out = (float*)d_out;

    // workspace layout (~105 MB)
    const size_t NROW = (size_t)N_NODES * FDIM;
    unsigned short* qb  = (unsigned short*)d_ws;        // f16 (scaled q)
    unsigned short* vb  = qb + NROW;                    // f16
    unsigned short* ab  = vb + NROW;                    // f16 attn rows
    unsigned char*  kf8 = (unsigned char*)(ab + NROW);  // fp8, NROW bytes
    unsigned short* wbf = (unsigned short*)(kf8 + NROW);
    unsigned char* rank8 = (unsigned char*)(wbf + 4 * 16384);  // E bytes
    int* cnt     = (int*)(rank8 + ((N_EDGES + 63) & ~63));     // N*CNT_STRIDE
    int* tick    = cnt + (size_t)N_NODES * CNT_STRIDE;         // NXCD*CNT_STRIDE
    int* row_off = tick + NXCD * CNT_STRIDE;            // N entries (local excl)
    int* part    = row_off + N_NODES + 1;               // block totals -> prefixes
    int* csr_src = part + 512;                          // E entries

    const int gemmGrid = (N_NODES + 127) / 128;         // 782
    const int edgeGrid = (N_EDGES + 255) / 256;         // 6250
    const int nb       = (N_NODES + 255) / 256;         // 391 scan blocks

    // K1: weights -> frag-linear 16-bit, + zero cnt/tick
    hipLaunchKernelGGL(convert_w_kernel, dim3(64), dim3(256), 0, stream,
                       Wq, Wk, Wv, Wo, wbf, cnt, tick);

    // K2: XCD-local edge count + rank
    hipLaunchKernelGGL(count_rank_xcd_kernel, dim3(2048), dim3(256), 0, stream,
                       edst, cnt, rank8, tick, N_EDGES);

    // K3: fused QKV projection; q scaled by D^-0.5 * log2(e) for exp2 softmax
    GemmArgs qkv;
    qkv.W[0] = wbf;          qkv.b[0] = bq; qkv.out[0] = qb;  qkv.scale[0] = 0.25f * 1.4426950408889634f;
    qkv.W[1] = wbf + 16384;  qkv.b[1] = bk; qkv.out[1] = kf8; qkv.scale[1] = 1.0f;
    qkv.W[2] = wbf + 32768;  qkv.b[2] = bv; qkv.out[2] = vb;  qkv.scale[2] = 1.0f;
    hipLaunchKernelGGL((mfma_gemm_v2<3, true, false, 4>), dim3(gemmGrid), dim3(256), 0, stream,
                       feat, qkv, N_NODES);

    // K4/K5: scan
    hipLaunchKernelGGL(scan_a_kernel, dim3(nb), dim3(256), 0, stream, cnt, row_off, part, N_NODES);
    hipLaunchKernelGGL(scan_b_kernel, dim3(1), dim3(512), 0, stream, part, nb);

    // K6: single-launch phased scatter
    hipLaunchKernelGGL(scatter_all_kernel, dim3(edgeGrid * SCAT_PHASES), dim3(256), 0, stream,
                       esrc, edst, rank8, row_off, part, csr_src, N_EDGES, edgeGrid);

    // K7: fused attention -> f16 attn rows in ws
    hipLaunchKernelGGL(attn_kernel, dim3((N_NODES + 3) / 4), dim3(256), 0, stream,
                       qb, kf8, vb, row_off, part, csr_src, ab, N_NODES, N_EDGES);

    // K8: output projection: f16 attn rows -> fp32 d_out
    GemmArgs oprj;
    oprj.W[0] = wbf + 3 * 16384; oprj.b[0] = bo; oprj.out[0] = out; oprj.scale[0] = 1.0f;
    hipLaunchKernelGGL((mfma_gemm_v2<1, false, true, 2>), dim3(gemmGrid), dim3(256), 0, stream,
                       ab, oprj, N_NODES);
}

// Round 10
// 222.483 us; speedup vs baseline: 1.2811x; 1.2811x over previous
//
#include <hip/hip_runtime.h>
#include <math.h>

#define N_NODES 100000
#define N_EDGES 1600000
#define FDIM 128
#define NHEAD 8
#define HDIM 16
#define NBUK 391        // ceil(N_NODES/256) buckets of 256 dst nodes
#define NPART 400       // partition blocks
#define PCHUNK 4000     // edges per partition block (NPART*PCHUNK == N_EDGES)

using bf16x8 = __attribute__((ext_vector_type(8))) short;
using half8  = __attribute__((ext_vector_type(8))) _Float16;
using f32x4  = __attribute__((ext_vector_type(4))) float;
using f32x2  = __attribute__((ext_vector_type(2))) float;

__device__ inline unsigned short f2bf(float f) {
    union { float f; unsigned int u; } x; x.f = f;
    unsigned int u = x.u;
    return (unsigned short)((u + 0x7fffu + ((u >> 16) & 1u)) >> 16);   // RNE
}
__device__ inline unsigned short f2h(float f) {
    _Float16 h = (_Float16)f;
    return __builtin_bit_cast(unsigned short, h);
}
__device__ inline unsigned int packh2(float a, float b) {
    return (unsigned int)f2h(a) | ((unsigned int)f2h(b) << 16);
}
__device__ inline float h_lo(unsigned int u) {
    return (float)__builtin_bit_cast(_Float16, (unsigned short)(u & 0xffffu));
}
__device__ inline float h_hi(unsigned int u) {
    return (float)__builtin_bit_cast(_Float16, (unsigned short)(u >> 16));
}
__device__ inline float exp2_fast(float x) {
#if __has_builtin(__builtin_amdgcn_exp2f)
    return __builtin_amdgcn_exp2f(x);
#else
    return __expf(x * 0.6931471805599453f);
#endif
}

// ---- fp8 e4m3 encode/decode (HW cvt on gfx950; SW fallback) ---------------
#if __has_builtin(__builtin_amdgcn_cvt_pk_fp8_f32)
__device__ inline unsigned char fp8_enc(float x) {
    return (unsigned char)(__builtin_amdgcn_cvt_pk_fp8_f32(x, x, 0, false) & 0xff);
}
#else
__device__ inline unsigned char fp8_enc(float x) {
    unsigned int u = __builtin_bit_cast(unsigned int, x);
    unsigned int s = (u >> 24) & 0x80;
    float ax = fabsf(x);
    if (!(ax >= 0.001953125f)) {
        int m = (int)(ax * 512.f + 0.5f);
        return (unsigned char)(s | (unsigned)(m > 7 ? 7 : m));
    }
    if (ax > 448.f) return (unsigned char)(s | 0x7e);
    int e; float fr = frexpf(ax, &e);
    int q = (int)(fr * 16.f + 0.5f);
    if (q == 16) { q = 8; e += 1; }
    int exp = e - 1 + 7;
    if (exp <= 0) { int m = (int)(ax * 512.f + 0.5f); return (unsigned char)(s | (unsigned)(m > 7 ? 7 : m)); }
    if (exp > 15) return (unsigned char)(s | 0x7e);
    return (unsigned char)(s | (exp << 3) | (q & 7));
}
#endif

#if __has_builtin(__builtin_amdgcn_cvt_pk_f32_fp8)
#define FP8_HW_DECODE 1
#else
__device__ inline float fp8_dec_sw(unsigned char b) {
    int s = b >> 7, e = (b >> 3) & 15, m = b & 7;
    float v = (e == 0) ? ldexpf((float)m, -9) : ldexpf((float)(8 + m), e - 10);
    return s ? -v : v;
}
#endif

// dot of 16 fp8 (one head's k row, as uint4) with 16 f32 q values (as 8 pairs)
__device__ inline float dot_fp8_16(uint4 kr, const f32x2* __restrict__ qq2) {
#ifdef FP8_HW_DECODE
    f32x2 a = {0.f, 0.f};
    f32x2 p;
    p = __builtin_amdgcn_cvt_pk_f32_fp8(kr.x, false); a += p * qq2[0];
    p = __builtin_amdgcn_cvt_pk_f32_fp8(kr.x, true);  a += p * qq2[1];
    p = __builtin_amdgcn_cvt_pk_f32_fp8(kr.y, false); a += p * qq2[2];
    p = __builtin_amdgcn_cvt_pk_f32_fp8(kr.y, true);  a += p * qq2[3];
    p = __builtin_amdgcn_cvt_pk_f32_fp8(kr.z, false); a += p * qq2[4];
    p = __builtin_amdgcn_cvt_pk_f32_fp8(kr.z, true);  a += p * qq2[5];
    p = __builtin_amdgcn_cvt_pk_f32_fp8(kr.w, false); a += p * qq2[6];
    p = __builtin_amdgcn_cvt_pk_f32_fp8(kr.w, true);  a += p * qq2[7];
    return a[0] + a[1];
#else
    const float* qq = (const float*)qq2;
    float s = 0.f;
    unsigned int wds[4] = {kr.x, kr.y, kr.z, kr.w};
#pragma unroll
    for (int i = 0; i < 4; ++i)
#pragma unroll
        for (int j = 0; j < 4; ++j)
            s = fmaf(fp8_dec_sw((wds[i] >> (8 * j)) & 0xff), qq[i * 4 + j], s);
    return s;
#endif
}

// ---------------------------------------------------------------------------
// Weights -> frag-linear layout (round 5). No other duties.
// ---------------------------------------------------------------------------
__global__ __launch_bounds__(256) void convert_w_kernel(
    const float* __restrict__ W0, const float* __restrict__ W1,
    const float* __restrict__ W2, const float* __restrict__ W3,
    unsigned short* __restrict__ out)
{
    int i = blockIdx.x * 256 + threadIdx.x;   // 0..16383
    int j  = i & 7;
    int l  = (i >> 3) & 63;
    int fk = i >> 9;                           // 0..31
    int ks = fk & 3, nf = fk >> 2;
    int s = (nf * 16 + (l & 15)) * FDIM + ks * 32 + (l >> 4) * 8 + j;
    out[i]             = f2bf(W0[s]);
    out[16384 + i]     = f2bf(W1[s]);
    out[2 * 16384 + i] = f2bf(W2[s]);
    out[3 * 16384 + i] = f2h(W3[s]);
}

// ---------------------------------------------------------------------------
// CSR build, zero global atomics (two-level counting sort, LDS atomics only).
// P1: per-partition-block LDS histogram over 391 dst buckets.
// ---------------------------------------------------------------------------
__global__ __launch_bounds__(256) void csr_hist_kernel(
    const int* __restrict__ edst, int* __restrict__ cntmatT)
{
    __shared__ int hist[NBUK];
    for (int b = threadIdx.x; b < NBUK; b += 256) hist[b] = 0;
    __syncthreads();
    const int c0 = blockIdx.x * PCHUNK;
    const int ce = min(c0 + PCHUNK, N_EDGES);
    for (int i = c0 + threadIdx.x; i < ce; i += 256) {
        int d = __builtin_nontemporal_load(&edst[i]);
        atomicAdd(&hist[d >> 8], 1);
    }
    __syncthreads();
    for (int b = threadIdx.x; b < NBUK; b += 256)
        cntmatT[b * NPART + blockIdx.x] = hist[b];
}

// P2a: per-bucket exclusive prefix over partition blocks + bucket totals.
__global__ __launch_bounds__(512) void csr_colscan_kernel(
    const int* __restrict__ cntmatT, int* __restrict__ preT, int* __restrict__ colsum)
{
    __shared__ int s[512];
    const int t = threadIdx.x, buk = blockIdx.x;
    int x = (t < NPART) ? cntmatT[buk * NPART + t] : 0;
    s[t] = x;
    __syncthreads();
    for (int off = 1; off < 512; off <<= 1) {
        int v = (t >= off) ? s[t - off] : 0;
        __syncthreads();
        s[t] += v;
        __syncthreads();
    }
    if (t < NPART) preT[buk * NPART + t] = s[t] - x;
    if (t == NPART - 1) colsum[buk] = s[t];
}

// P2b: bucket base offsets (exclusive scan of totals); row_off[N] = E.
__global__ __launch_bounds__(512) void csr_basescan_kernel(
    const int* __restrict__ colsum, int* __restrict__ base, int* __restrict__ row_off)
{
    __shared__ int s[512];
    const int t = threadIdx.x;
    int x = (t < NBUK) ? colsum[t] : 0;
    s[t] = x;
    __syncthreads();
    for (int off = 1; off < 512; off <<= 1) {
        int v = (t >= off) ? s[t - off] : 0;
        __syncthreads();
        s[t] += v;
        __syncthreads();
    }
    if (t < NBUK) base[t] = s[t] - x;
    if (t == 0) { base[NBUK] = N_EDGES; row_off[N_NODES] = N_EDGES; }
}

// P3: partition edges into bucket-grouped (src,dst) pairs via LDS cursors.
__global__ __launch_bounds__(256) void csr_partition_kernel(
    const int* __restrict__ esrc, const int* __restrict__ edst,
    const int* __restrict__ preT, const int* __restrict__ base,
    uint2* __restrict__ bpair)
{
    __shared__ int cur[NBUK];
    for (int b = threadIdx.x; b < NBUK; b += 256)
        cur[b] = base[b] + preT[b * NPART + blockIdx.x];
    __syncthreads();
    const int c0 = blockIdx.x * PCHUNK;
    const int ce = min(c0 + PCHUNK, N_EDGES);
    for (int i = c0 + threadIdx.x; i < ce; i += 256) {
        int d = __builtin_nontemporal_load(&edst[i]);
        int s = __builtin_nontemporal_load(&esrc[i]);
        int slot = atomicAdd(&cur[d >> 8], 1);
        bpair[slot] = make_uint2((unsigned)s, (unsigned)d);
    }
}

// P4: per-bucket (256 dst nodes) local counting sort: exact row_off + csr_src.
__global__ __launch_bounds__(256) void csr_bucket_kernel(
    const uint2* __restrict__ bpair, const int* __restrict__ base,
    int* __restrict__ row_off, int* __restrict__ csr_src)
{
    __shared__ int cnt2[256], s[256], cur[256];
    const int buk = blockIdx.x, t = threadIdx.x;
    const int b0 = base[buk];
    const int sz = base[buk + 1] - b0;
    const int nb0 = buk << 8;

    cnt2[t] = 0;
    __syncthreads();
    for (int i = t; i < sz; i += 256)
        atomicAdd(&cnt2[bpair[b0 + i].y & 255u], 1);
    __syncthreads();

    int x = cnt2[t];
    s[t] = x;
    __syncthreads();
    for (int off = 1; off < 256; off <<= 1) {
        int v = (t >= off) ? s[t - off] : 0;
        __syncthreads();
        s[t] += v;
        __syncthreads();
    }
    int excl = s[t] - x;
    cur[t] = excl;
    if (nb0 + t < N_NODES) row_off[nb0 + t] = b0 + excl;
    __syncthreads();

    for (int i = t; i < sz; i += 256) {
        uint2 p = bpair[b0 + i];
        int r = atomicAdd(&cur[p.y & 255u], 1);
        csr_src[b0 + r] = (int)p.x;
    }
}

// ---------------------------------------------------------------------------
// MFMA GEMM v2 (round 5 structure): latency-tolerant 128-row blocks.
// ---------------------------------------------------------------------------
struct GemmArgs {
    const unsigned short* W[3];
    const float* b[3];
    void* out[3];
    float scale[3];
};

template<int NP, bool IN_F32, bool MFMA_F16, int OUTM>
__global__ __launch_bounds__(256, 2) void mfma_gemm_v2(
    const void* __restrict__ Ain, GemmArgs ga, int nrows)
{
    __shared__ unsigned short A_s[128][136];   // 34816 B; reused for O repack
    __shared__ unsigned short W_sh[8192];      // 16 KB: half of one projection's W

    const int t  = threadIdx.x;
    const int r0 = blockIdx.x * 128;

#pragma unroll
    for (int it = 0; it < 8; ++it) {
        int i = t + it * 256;
        int r = i >> 4, c8 = (i & 15) << 3;
        int gr = r0 + r;
        if (IN_F32) {
            float4 v0 = make_float4(0.f, 0.f, 0.f, 0.f), v1 = v0;
            if (gr < nrows) {
                const float* Af = (const float*)Ain;
                v0 = *(const float4*)&Af[(size_t)gr * FDIM + c8];
                v1 = *(const float4*)&Af[(size_t)gr * FDIM + c8 + 4];
            }
            uint4 pk;
            pk.x = (unsigned)f2bf(v0.x) | ((unsigned)f2bf(v0.y) << 16);
            pk.y = (unsigned)f2bf(v0.z) | ((unsigned)f2bf(v0.w) << 16);
            pk.z = (unsigned)f2bf(v1.x) | ((unsigned)f2bf(v1.y) << 16);
            pk.w = (unsigned)f2bf(v1.z) | ((unsigned)f2bf(v1.w) << 16);
            *(uint4*)&A_s[r][c8] = pk;
        } else {
            uint4 v = make_uint4(0u, 0u, 0u, 0u);
            if (gr < nrows) {
                const unsigned short* Ab = (const unsigned short*)Ain;
                v = *(const uint4*)&Ab[(size_t)gr * FDIM + c8];
            }
            *(uint4*)&A_s[r][c8] = v;
        }
    }
    __syncthreads();

    const int w  = t >> 6, l = t & 63;
    const int lr = l & 15, lk = l >> 4;

    bf16x8 a[2][4];
#pragma unroll
    for (int rg = 0; rg < 2; ++rg)
#pragma unroll
        for (int ks = 0; ks < 4; ++ks)
            a[rg][ks] = *(const bf16x8*)&A_s[w * 32 + rg * 16 + lr][ks * 32 + lk * 8];

#pragma unroll
    for (int p = 0; p < NP; ++p) {
        const unsigned short* Wsrc = ga.W[p];
        f32x4 acc[2][8];
#pragma unroll
        for (int rg = 0; rg < 2; ++rg)
#pragma unroll
            for (int nf = 0; nf < 8; ++nf) acc[rg][nf] = (f32x4){0.f, 0.f, 0.f, 0.f};

#pragma unroll
        for (int h = 0; h < 2; ++h) {
#pragma unroll
            for (int it = 0; it < 4; ++it) {
                int chunk = t + it * 256;
                *(uint4*)&W_sh[chunk * 8] = *(const uint4*)&Wsrc[h * 8192 + chunk * 8];
            }
            __syncthreads();
#pragma unroll
            for (int nfl = 0; nfl < 4; ++nfl) {
                int nf = h * 4 + nfl;
#pragma unroll
                for (int ks = 0; ks < 4; ++ks) {
                    bf16x8 bfr = *(const bf16x8*)&W_sh[((nfl * 4 + ks) * 64 + l) * 8];
                    if (MFMA_F16) {
                        acc[0][nf] = __builtin_amdgcn_mfma_f32_16x16x32_f16(
                            __builtin_bit_cast(half8, a[0][ks]), __builtin_bit_cast(half8, bfr),
                            acc[0][nf], 0, 0, 0);
                        acc[1][nf] = __builtin_amdgcn_mfma_f32_16x16x32_f16(
                            __builtin_bit_cast(half8, a[1][ks]), __builtin_bit_cast(half8, bfr),
                            acc[1][nf], 0, 0, 0);
                    } else {
                        acc[0][nf] = __builtin_amdgcn_mfma_f32_16x16x32_bf16(a[0][ks], bfr, acc[0][nf], 0, 0, 0);
                        acc[1][nf] = __builtin_amdgcn_mfma_f32_16x16x32_bf16(a[1][ks], bfr, acc[1][nf], 0, 0, 0);
                    }
                }
            }
            __syncthreads();
        }

        const float* bias = ga.b[p];
        const float  scl  = ga.scale[p];
        const int    mode = (OUTM >> (2 * p)) & 3;

        if (mode == 0) {
            unsigned short* Oh = &A_s[0][0];
#pragma unroll
            for (int rg = 0; rg < 2; ++rg)
#pragma unroll
                for (int nf = 0; nf < 8; ++nf) {
                    int col = nf * 16 + lr;
                    float bv = bias[col];
#pragma unroll
                    for (int j = 0; j < 4; ++j)
                        Oh[(w * 32 + rg * 16 + lk * 4 + j) * 136 + col] = f2h((acc[rg][nf][j] + bv) * scl);
                }
            __syncthreads();
            unsigned short* outp = (unsigned short*)ga.out[p];
#pragma unroll
            for (int it = 0; it < 8; ++it) {
                int i = t + it * 256;
                int r = i >> 4, c8 = (i & 15) << 3;
                if (r0 + r < nrows)
                    *(uint4*)&outp[(size_t)(r0 + r) * FDIM + c8] = *(const uint4*)&Oh[r * 136 + c8];
            }
        } else if (mode == 1) {
            unsigned char* O8 = (unsigned char*)A_s;
#pragma unroll
            for (int rg = 0; rg < 2; ++rg)
#pragma unroll
                for (int nf = 0; nf < 8; ++nf) {
                    int col = nf * 16 + lr;
                    float bv = bias[col];
#pragma unroll
                    for (int j = 0; j < 4; ++j)
                        O8[(w * 32 + rg * 16 + lk * 4 + j) * 144 + col] = fp8_enc((acc[rg][nf][j] + bv) * scl);
                }
            __syncthreads();
            unsigned char* outp = (unsigned char*)ga.out[p];
#pragma unroll
            for (int it = 0; it < 4; ++it) {
                int i = t + it * 256;
                int r = i >> 3, c16 = (i & 7) << 4;
                if (r0 + r < nrows)
                    *(uint4*)&outp[(size_t)(r0 + r) * FDIM + c16] = *(const uint4*)&O8[r * 144 + c16];
            }
        } else {
            float* outp = (float*)ga.out[p];
#pragma unroll
            for (int rg = 0; rg < 2; ++rg)
#pragma unroll
                for (int nf = 0; nf < 8; ++nf) {
                    int col = nf * 16 + lr;
                    float bv = bias[col];
                    int row = r0 + w * 32 + rg * 16 + lk * 4;
#pragma unroll
                    for (int j = 0; j < 4; ++j)
                        if (row + j < nrows)
                            outp[(size_t)(row + j) * FDIM + col] = (acc[rg][nf][j] + bv) * scl;
                }
        }
    }
}

// ---------------------------------------------------------------------------
// Fused edge-softmax attention (inner loops unchanged; plain row_off again).
// ---------------------------------------------------------------------------
__global__ __launch_bounds__(256) void attn_kernel(
    const unsigned short* __restrict__ q, const unsigned char* __restrict__ kf8,
    const unsigned short* __restrict__ v,
    const int* __restrict__ row_off, const int* __restrict__ csr_src,
    unsigned short* __restrict__ out, int nnodes)
{
    __shared__ float q_s[4][NHEAD][18];   // head stride 18 words: conflict-free
    __shared__ float p_s[4][64][NHEAD];
    __shared__ int   src_s[4][64];

    const int w = threadIdx.x >> 6;
    const int l = threadIdx.x & 63;
    const int node = blockIdx.x * 4 + w;
    if (node >= nnodes) return;

    {   // stage q row (pre-scaled by 0.25*log2e) as f32 pairs
        unsigned int qv = *(const unsigned int*)&q[(size_t)node * FDIM + l * 2];
        *(f32x2*)&q_s[w][l >> 3][(l & 7) * 2] = (f32x2){h_lo(qv), h_hi(qv)};
    }

    const int e_l = l >> 3, h_sc = l & 7;                    // score role
    const int e2 = l >> 4, h_ag = (l >> 1) & 7, dq = l & 1;  // agg role
    const int vo = h_ag * HDIM + dq * 8;                     // ushort offset

    const int start = row_off[node];
    const int end   = row_off[node + 1];

    float z_run = 0.f;
    f32x2 acc[4] = {{0.f,0.f},{0.f,0.f},{0.f,0.f},{0.f,0.f}};   // 8 dims

    const f32x2* qq2 = (const f32x2*)&q_s[w][h_sc][0];

    for (int c0 = start; c0 < end; c0 += 64) {
        const int cn = min(64, end - c0);

        for (int i = l; i < cn; i += 64)
            src_s[w][i] = csr_src[c0 + i];

        // --- scores: p = exp2(k.q'), 4-deep batched 16B k loads -----------
        for (int base = 0; base < cn; base += 32) {
            uint4 kr[4];
#pragma unroll
            for (int it = 0; it < 4; ++it) {
                int ei = base + it * 8 + e_l;
                if (ei < cn)
                    kr[it] = *(const uint4*)&kf8[(size_t)src_s[w][ei] * FDIM + h_sc * 16];
            }
#pragma unroll
            for (int it = 0; it < 4; ++it) {
                int ei = base + it * 8 + e_l;
                if (ei < cn) {
                    float p = exp2_fast(dot_fp8_16(kr[it], qq2));
                    p_s[w][ei][h_sc] = p;
                    z_run += p;
                }
            }
        }

        // --- aggregation: 4 edges per iteration, 16B v load per lane ------
        for (int base = 0; base < cn; base += 4) {
            int e  = base + e2;
            int ec = min(e, cn - 1);
            float p = (e < cn) ? p_s[w][e][h_ag] : 0.f;
            uint4 vv = *(const uint4*)&v[(size_t)src_s[w][ec] * FDIM + vo];
            f32x2 p2 = {p, p};
            acc[0] += p2 * (f32x2){h_lo(vv.x), h_hi(vv.x)};
            acc[1] += p2 * (f32x2){h_lo(vv.y), h_hi(vv.y)};
            acc[2] += p2 * (f32x2){h_lo(vv.z), h_hi(vv.z)};
            acc[3] += p2 * (f32x2){h_lo(vv.w), h_hi(vv.w)};
        }
    }

    // z: sum across e_l groups (lanes sharing h_sc) — once per node
#pragma unroll
    for (int mask = 8; mask < 64; mask <<= 1)
        z_run += __shfl_xor(z_run, mask, 64);

    // acc: sum across the 4 e2 groups (masks 16, 32)
#pragma unroll
    for (int mask = 16; mask < 64; mask <<= 1)
#pragma unroll
        for (int i = 0; i < 4; ++i) {
            acc[i][0] += __shfl_xor(acc[i][0], mask, 64);
            acc[i][1] += __shfl_xor(acc[i][1], mask, 64);
        }

    float z_ag = __shfl(z_run, h_ag, 64);   // lane h_ag holds z for head h_ag

    if (e2 == 0) {
        uint4 o = make_uint4(0u, 0u, 0u, 0u);
        if (end > start) {
            float rz = 1.0f / z_ag;
            o.x = packh2(acc[0][0] * rz, acc[0][1] * rz);
            o.y = packh2(acc[1][0] * rz, acc[1][1] * rz);
            o.z = packh2(acc[2][0] * rz, acc[2][1] * rz);
            o.w = packh2(acc[3][0] * rz, acc[3][1] * rz);
        }
        *(uint4*)&out[(size_t)node * FDIM + vo] = o;
    }
}

// ---------------------------------------------------------------------------
extern "C" void kernel_launch(void* const* d_in, const int* in_sizes, int n_in,
                              void* d_out, int out_size, void* d_ws, size_t ws_size,
                              hipStream_t stream)
{
    const float* feat = (const float*)d_in[0];
    const int*   esrc = (const int*)d_in[1];
    const int*   edst = (const int*)d_in[2];
    const float* Wq   = (const float*)d_in[3];
    const float* bq   = (const float*)d_in[4];
    const float* Wk   = (const float*)d_in[5];
    const float* bk   = (const float*)d_in[6];
    const float* Wv   = (const float*)d_in[7];
    const float* bv   = (const float*)d_in[8];
    const float* Wo   = (const float*)d_in[9];
    const float* bo   = (const float*)d_in[10];
    float* out = (float*)d_out;

    // workspace layout (~112 MB)
    const size_t NROW = (size_t)N_NODES * FDIM;
    unsigned short* qb  = (unsigned short*)d_ws;        // f16 (scaled q)
    unsigned short* vb  = qb + NROW;                    // f16
    unsigned short* ab  = vb + NROW;                    // f16 attn rows
    unsigned char*  kf8 = (unsigned char*)(ab + NROW);  // fp8, NROW bytes
    unsigned short* wbf = (unsigned short*)(kf8 + NROW);
    int* cntmatT = (int*)(wbf + 4 * 16384);             // NBUK*NPART
    int* preT    = cntmatT + NBUK * NPART;              // NBUK*NPART
    int* colsum  = preT + NBUK * NPART;                 // 512
    int* base    = colsum + 512;                        // 512 (NBUK+1 used)
    uint2* bpair = (uint2*)(base + 512);                // E pairs (8B each)
    int* row_off = (int*)(bpair + N_EDGES);             // N+1
    int* csr_src = row_off + N_NODES + 1;               // E

    const int gemmGrid = (N_NODES + 127) / 128;         // 782

    // K1: weights -> frag-linear 16-bit
    hipLaunchKernelGGL(convert_w_kernel, dim3(64), dim3(256), 0, stream,
                       Wq, Wk, Wv, Wo, wbf);

    // K2: fused QKV projection; q scaled by D^-0.5 * log2(e) for exp2 softmax
    GemmArgs qkv;
    qkv.W[0] = wbf;          qkv.b[0] = bq; qkv.out[0] = qb;  qkv.scale[0] = 0.25f * 1.4426950408889634f;
    qkv.W[1] = wbf + 16384;  qkv.b[1] = bk; qkv.out[1] = kf8; qkv.scale[1] = 1.0f;
    qkv.W[2] = wbf + 32768;  qkv.b[2] = bv; qkv.out[2] = vb;  qkv.scale[2] = 1.0f;
    hipLaunchKernelGGL((mfma_gemm_v2<3, true, false, 4>), dim3(gemmGrid), dim3(256), 0, stream,
                       feat, qkv, N_NODES);

    // K3..K7: CSR build, zero global atomics
    hipLaunchKernelGGL(csr_hist_kernel, dim3(NPART), dim3(256), 0, stream, edst, cntmatT);
    hipLaunchKernelGGL(csr_colscan_kernel, dim3(NBUK), dim3(512), 0, stream, cntmatT, preT, colsum);
    hipLaunchKernelGGL(csr_basescan_kernel, dim3(1), dim3(512), 0, stream, colsum, base, row_off);
    hipLaunchKernelGGL(csr_partition_kernel, dim3(NPART), dim3(256), 0, stream,
                       esrc, edst, preT, base, bpair);
    hipLaunchKernelGGL(csr_bucket_kernel, dim3(NBUK), dim3(256), 0, stream,
                       bpair, base, row_off, csr_src);

    // K8: fused attention -> f16 attn rows in ws
    hipLaunchKernelGGL(attn_kernel, dim3((N_NODES + 3) / 4), dim3(256), 0, stream,
                       qb, kf8, vb, row_off, csr_src, ab, N_NODES);

    // K9: output projection: f16 attn rows -> fp32 d_out
    GemmArgs oprj;
    oprj.W[0] = wbf + 3 * 16384; oprj.b[0] = bo; oprj.out[0] = out; oprj.scale[0] = 1.0f;
    hipLaunchKernelGGL((mfma_gemm_v2<1, false, true, 2>), dim3(gemmGrid), dim3(256), 0, stream,
                       ab, oprj, N_NODES);
}